// Round 4
// baseline (206.424 us; speedup 1.0000x reference)
//
#include <hip/hip_runtime.h>
#include <hip/hip_bf16.h>

// x: (32, 512) int32 in [0,16); pos_enc: (5000, 384) f32;
// out: (32, T, 384) f32, T = out_size / (32*384).
//
// Two-kernel plan:
//  K1 (32 blocks x 64): wave cumsum of x[b,:], then directly scatter the
//     per-output-row source index rowsrc[b,t] = position-within-token
//     (0..15) or -1 for the zero tail. 32*T ints (~500KB) in d_ws.
//  K2 (fill-shaped): grid-stride, one float4 per thread-iter, value =
//     pe[rowsrc[row]*96 + col] or 0. pe working set is 16 rows = 24KB
//     (L1-resident); rowsrc reads are wave-broadcast. Pure streaming
//     writes dominate: ~199MB -> ~31us at fill rate.

#define B 32
#define L 512
#define D 384
#define D4 (D / 4)   // 96 float4 per row

// Native vector type: __builtin_nontemporal_store rejects HIP_vector_type.
typedef float f32x4 __attribute__((ext_vector_type(4)));

// ---------------------------------------------------------------------------
// K1: cumsum + plan. One block per batch row, 64 lanes.
// ---------------------------------------------------------------------------
__global__ __launch_bounds__(64) void pe_plan_kernel(
    const int* __restrict__ x, int* __restrict__ rowsrc, int T) {
  const int b = blockIdx.x;
  const int lane = threadIdx.x;  // 0..63
  const int base = b * L + lane * 8;

  const int4* xr = reinterpret_cast<const int4*>(x + base);
  int4 a = xr[0];
  int4 c4 = xr[1];
  int v[8] = {a.x, a.y, a.z, a.w, c4.x, c4.y, c4.z, c4.w};

  int pref[8];
  int s = 0;
#pragma unroll
  for (int k = 0; k < 8; ++k) { s += v[k]; pref[k] = s; }

  // Inclusive wave scan of per-lane sums (wave = 64 on gfx950).
  int acc = s;
#pragma unroll
  for (int off = 1; off < 64; off <<= 1) {
    int n = __shfl_up(acc, off);
    if (lane >= off) acc += n;
  }
  const int lane_off = acc - s;        // exclusive prefix for this lane
  const int total = __shfl(acc, 63);   // row total (= sum of x[b,:])

  int* rs = rowsrc + (size_t)b * T;

  // Each lane fills the rowsrc segments of its own 8 tokens (disjoint
  // contiguous ranges; adjacent lanes cover adjacent ranges).
#pragma unroll
  for (int k = 0; k < 8; ++k) {
    const int c = v[k];
    const int st = lane_off + pref[k] - c;  // start row of token k
    for (int p = 0; p < c; ++p) rs[st + p] = p;
  }

  // Zero tail: rows [total, T) get -1.
  for (int t = total + lane; t < T; t += 64) rs[t] = -1;
}

// ---------------------------------------------------------------------------
// K2: fill-shaped writer. One float4 per thread-iteration, linear layout.
// ---------------------------------------------------------------------------
__global__ __launch_bounds__(256) void pe_write_kernel(
    const f32x4* __restrict__ pe, const int* __restrict__ rowsrc,
    f32x4* __restrict__ out, int n4) {
  const int stride = gridDim.x * 256;
  for (int i = blockIdx.x * 256 + threadIdx.x; i < n4; i += stride) {
    const int row = i / D4;          // const-divisor -> magic mul
    const int col = i - row * D4;
    const int p = rowsrc[row];       // wave-broadcast, L1/L2-hit
    f32x4 v = {0.f, 0.f, 0.f, 0.f};
    if (p >= 0) v = pe[p * D4 + col];  // 24KB working set, L1-hit
    __builtin_nontemporal_store(v, &out[i]);
  }
}

// ---------------------------------------------------------------------------
extern "C" void kernel_launch(void* const* d_in, const int* in_sizes, int n_in,
                              void* d_out, int out_size, void* d_ws, size_t ws_size,
                              hipStream_t stream) {
  const int* x = (const int*)d_in[0];       // (32, 512) int32
  const float* pe = (const float*)d_in[1];  // (5000, 384) f32
  float* out = (float*)d_out;               // (32, T, 384) f32

  const int T = out_size / (B * D);

  int* rowsrc = (int*)d_ws;  // 32*T ints

  pe_plan_kernel<<<B, 64, 0, stream>>>(x, rowsrc, T);

  const int n4 = out_size / 4;
  int blocks = (n4 + 255) / 256;
  if (blocks > 2048) blocks = 2048;
  pe_write_kernel<<<blocks, 256, 0, stream>>>(
      (const f32x4*)pe, rowsrc, (f32x4*)out, n4);
}